// Round 3
// baseline (941.457 us; speedup 1.0000x reference)
//
#include <hip/hip_runtime.h>
#include <hip/hip_bf16.h>

// Problem constants
constexpr int BB = 4;     // batch
constexpr int NN = 2048;  // nodes
constexpr int EE = 4096;  // edges
constexpr int DD = 256;   // feature dim

// Sizes (floats)
constexpr long VOUT_SZ = (long)BB * NN * DD;          //  2,097,152
constexpr long E_SZ    = (long)BB * EE * DD;          //  4,194,304
constexpr long U_SZ    = (long)BB * DD;               //  1,024
constexpr long ADJ_SZ  = (long)BB * NN * NN;          // 16,777,216
constexpr long CON_SZ  = (long)BB * NN * EE;          // 33,554,432
constexpr long EADJ_SZ = (long)BB * EE * EE;          // 67,108,864

// Output segment float offsets (concat in return order)
constexpr long OUT_E    = VOUT_SZ;
constexpr long OUT_U    = OUT_E + E_SZ;
constexpr long OUT_ADJ  = OUT_U + U_SZ;
constexpr long OUT_CON  = OUT_ADJ + ADJ_SZ;
constexpr long OUT_EADJ = OUT_CON + CON_SZ;

constexpr int  MM_BLOCKS   = 64;    // 4 batches * 16 n-tiles (128 rows), full-D tiles
constexpr int  COPY_BLOCKS = 960;
constexpr long NEED_WS     = 33554432L + 4194304L + 8388608L;  // adjT+vT+eT = 46,137,344 B

using bf16x4 = __attribute__((ext_vector_type(4))) __bf16;
using bf16x8 = __attribute__((ext_vector_type(8))) __bf16;
using f32x4  = __attribute__((ext_vector_type(4))) float;
using f32x4v = __attribute__((ext_vector_type(4))) float;  // NT-safe vector type

// ---------------------------------------------------------------------------
// prep: transpose + f32->bf16 convert (adj->adjT [n][m], v->vT [d][m],
// e->eT [d][e]) so GEMM staging reads are k-contiguous. FUSED: also writes
// the verbatim f32 pass-through copies of adj and e_in into d_out (saves a
// re-read of 83 MB in the copy phase).
// ---------------------------------------------------------------------------
__global__ __launch_bounds__(256) void prep_kernel(
    const float* __restrict__ v_in, const float* __restrict__ e_in,
    const float* __restrict__ adj,
    __bf16* __restrict__ adjT, __bf16* __restrict__ vT, __bf16* __restrict__ eT,
    float* __restrict__ out)
{
    __shared__ float tile[64][65];  // +1 pad: conflict-free transposed reads

    int bid = blockIdx.x;
    const float* in; __bf16* outT; float* pass; int R, C, t;
    if (bid < 4096)      { in = adj;  outT = adjT; R = NN; C = NN; t = bid;
                           pass = out + OUT_ADJ; }
    else if (bid < 4608) { in = v_in; outT = vT;   R = NN; C = DD; t = bid - 4096;
                           pass = nullptr; }
    else                 { in = e_in; outT = eT;   R = EE; C = DD; t = bid - 4608;
                           pass = out + OUT_E; }

    int perBatch = (R >> 6) * (C >> 6);
    int b  = t / perBatch;
    int tt = t % perBatch;
    int tilesC = C >> 6;
    int tr = tt / tilesC, tc = tt % tilesC;

    const size_t base = (size_t)b * R * C + (size_t)(tr * 64) * C + tc * 64;
    const float* inb  = in + base;
    float*       pb   = pass ? pass + base : nullptr;
    __bf16*     outb  = outT + (size_t)b * R * C + (size_t)(tc * 64) * R + tr * 64;

    int tid = threadIdx.x;
    #pragma unroll
    for (int it = 0; it < 4; ++it) {
        int q = tid + it * 256;           // 0..1023
        int r = q >> 4, c4 = (q & 15) << 2;
        f32x4v fv = *reinterpret_cast<const f32x4v*>(&inb[(size_t)r * C + c4]);
        tile[r][c4 + 0] = fv.x; tile[r][c4 + 1] = fv.y;
        tile[r][c4 + 2] = fv.z; tile[r][c4 + 3] = fv.w;
        if (pb) __builtin_nontemporal_store(fv,
                    reinterpret_cast<f32x4v*>(&pb[(size_t)r * C + c4]));
    }
    __syncthreads();
    #pragma unroll
    for (int it = 0; it < 4; ++it) {
        int q = tid + it * 256;
        int c = q >> 4, r4 = (q & 15) << 2;
        bf16x4 h = { (__bf16)tile[r4 + 0][c], (__bf16)tile[r4 + 1][c],
                     (__bf16)tile[r4 + 2][c], (__bf16)tile[r4 + 3][c] };
        *reinterpret_cast<bf16x4*>(&outb[(size_t)c * R + r4]) = h;
    }
}

// ---------------------------------------------------------------------------
// mega: role-split blocks (512 threads each).
//   [0, MM_BLOCKS): 128x256 output-tile GEMM, v_out = v + adjT@v + conEd@e + u
//       8 waves (2x4), wave tile 64x64, mfma_f32_16x16x32_bf16.
//   [MM_BLOCKS, +COPY_BLOCKS): float4 grid-stride copy of u/conEd/edgeAdj.
// LDS: per-row XOR granule swizzle -> conflict-free b128 reads, ~free writes.
// ---------------------------------------------------------------------------
__global__ __launch_bounds__(512) void mega_kernel(
    const float* __restrict__ v_in, const float* __restrict__ e_in,
    const float* __restrict__ u_in, const float* __restrict__ adj,
    const float* __restrict__ conEd, const float* __restrict__ edgeAdj,
    const __bf16* __restrict__ adjT, const __bf16* __restrict__ vT,
    const __bf16* __restrict__ eT, float* __restrict__ out, long eadjLimit4)
{
    __shared__ __bf16 As[128 * 64];  // [row n][k], 16 KB, swizzled
    __shared__ __bf16 Bs[256 * 64];  // [col d][k], 32 KB, swizzled

    const int bid = blockIdx.x;
    const int tid = threadIdx.x;

    if (bid < MM_BLOCKS) {
        const int b  = bid >> 4;        // 16 tiles per batch
        const int n0 = (bid & 15) << 7; // n-tile of 128

        const __bf16* adjT_b = adjT + (size_t)b * NN * NN;
        const __bf16* vT_b   = vT   + (size_t)b * DD * NN;
        const __bf16* eT_b   = eT   + (size_t)b * DD * EE;
        const float*  con_b  = conEd + (size_t)b * NN * EE;
        const float*  v_b    = v_in  + (size_t)b * NN * DD;
        const float*  u_b    = u_in  + (size_t)b * DD;

        const int lane = tid & 63, wid = tid >> 6;
        const int wr = wid >> 2, wc = wid & 3;   // waves 2x4 -> 64x64 each
        const int lr = lane & 15;
        const int lkq = lane >> 4;               // k quadrant 0..3

        f32x4 acc[4][4] = {};

        for (int phase = 0; phase < 2; ++phase) {
            const int K = phase ? EE : NN;
            const __bf16* bT = phase ? eT_b : vT_b;
            for (int k0 = 0; k0 < K; k0 += 64) {
                __syncthreads();
                if (phase == 0) {
                    // As[n][k] <- adjT_b[n0+n][k0..k0+63]  (bf16, k-contiguous)
                    #pragma unroll
                    for (int it = 0; it < 2; ++it) {
                        int q = tid + it * 512;      // 0..1023
                        int n = q >> 3, g = q & 7;
                        bf16x8 vv = *reinterpret_cast<const bf16x8*>(
                            &adjT_b[(size_t)(n0 + n) * NN + k0 + (g << 3)]);
                        *reinterpret_cast<bf16x8*>(&As[(n << 6) + ((g ^ (n & 7)) << 3)]) = vv;
                    }
                } else {
                    // As[n][k] <- convert(con_b[n0+n][k0..k0+63])  (f32 src)
                    #pragma unroll
                    for (int it = 0; it < 4; ++it) {
                        int q = tid + it * 512;      // 0..2047
                        int n = q >> 4, e4 = (q & 15) << 2;
                        f32x4v fv = *reinterpret_cast<const f32x4v*>(
                            &con_b[(size_t)(n0 + n) * EE + k0 + e4]);
                        bf16x4 h = { (__bf16)fv.x, (__bf16)fv.y, (__bf16)fv.z, (__bf16)fv.w };
                        *reinterpret_cast<bf16x4*>(
                            &As[(n << 6) + (((e4 >> 3) ^ (n & 7)) << 3) + (e4 & 7)]) = h;
                    }
                }
                // Bs[d][k] <- bT[d][k0..k0+63], all 256 d-rows
                #pragma unroll
                for (int it = 0; it < 4; ++it) {
                    int q = tid + it * 512;          // 0..2047
                    int dd = q >> 3, g = q & 7;
                    bf16x8 vv = *reinterpret_cast<const bf16x8*>(
                        &bT[(size_t)dd * K + k0 + (g << 3)]);
                    *reinterpret_cast<bf16x8*>(&Bs[(dd << 6) + ((g ^ (dd & 7)) << 3)]) = vv;
                }
                __syncthreads();

                #pragma unroll
                for (int ks = 0; ks < 2; ++ks) {
                    const int gk = (ks << 2) + lkq;  // k granule 0..7
                    bf16x8 a[4], bv[4];
                    #pragma unroll
                    for (int i = 0; i < 4; ++i) {
                        int row = (wr << 6) + (i << 4) + lr;
                        a[i] = *reinterpret_cast<const bf16x8*>(
                            &As[(row << 6) + ((gk ^ (row & 7)) << 3)]);
                    }
                    #pragma unroll
                    for (int j = 0; j < 4; ++j) {
                        int col = (wc << 6) + (j << 4) + lr;
                        bv[j] = *reinterpret_cast<const bf16x8*>(
                            &Bs[(col << 6) + ((gk ^ (col & 7)) << 3)]);
                    }
                    #pragma unroll
                    for (int i = 0; i < 4; ++i)
                        #pragma unroll
                        for (int j = 0; j < 4; ++j)
                            acc[i][j] = __builtin_amdgcn_mfma_f32_16x16x32_bf16(
                                a[i], bv[j], acc[i][j], 0, 0, 0);
                }
            }
        }

        // epilogue: v_out = acc + v_in + u
        float uv[4];
        #pragma unroll
        for (int j = 0; j < 4; ++j) uv[j] = u_b[(wc << 6) + (j << 4) + lr];
        #pragma unroll
        for (int i = 0; i < 4; ++i) {
            #pragma unroll
            for (int r = 0; r < 4; ++r) {
                int n = n0 + (wr << 6) + (i << 4) + (lkq << 2) + r;
                #pragma unroll
                for (int j = 0; j < 4; ++j) {
                    int col = (wc << 6) + (j << 4) + lr;
                    out[((size_t)b * NN + n) * DD + col] =
                        acc[i][j][r] + v_b[(size_t)n * DD + col] + uv[j];
                }
            }
        }
    } else {
        // ------- copy role: u, conEd, edgeAdj (adj & e done by prep) -------
        const long i0 = (long)(bid - MM_BLOCKS) * 512 + tid;
        const long stride = (long)COPY_BLOCKS * 512;

        const f32x4v* u4 = reinterpret_cast<const f32x4v*>(u_in);
        f32x4v*      ou4 = reinterpret_cast<f32x4v*>(out + OUT_U);
        for (long i = i0; i < U_SZ / 4; i += stride) ou4[i] = u4[i];

        const f32x4v* c4 = reinterpret_cast<const f32x4v*>(conEd);
        f32x4v*      oc4 = reinterpret_cast<f32x4v*>(out + OUT_CON);
        for (long i = i0; i < CON_SZ / 4; i += stride)
            __builtin_nontemporal_store(__builtin_nontemporal_load(&c4[i]), &oc4[i]);

        const f32x4v* g4 = reinterpret_cast<const f32x4v*>(edgeAdj);
        f32x4v*      og4 = reinterpret_cast<f32x4v*>(out + OUT_EADJ);
        for (long i = i0; i < eadjLimit4; i += stride)
            __builtin_nontemporal_store(__builtin_nontemporal_load(&g4[i]), &og4[i]);
    }
}

// tail copy for the fallback path (scratch lived in d_out tail): finishes the
// edgeAdj segment [start4, EADJ_SZ/4)
__global__ __launch_bounds__(256) void tail_copy_kernel(
    const float* __restrict__ edgeAdj, float* __restrict__ out, long start4)
{
    const long i0 = start4 + (long)blockIdx.x * 256 + threadIdx.x;
    const long stride = (long)gridDim.x * 256;
    const f32x4v* g4 = reinterpret_cast<const f32x4v*>(edgeAdj);
    f32x4v*      og4 = reinterpret_cast<f32x4v*>(out + OUT_EADJ);
    for (long i = i0; i < EADJ_SZ / 4; i += stride)
        __builtin_nontemporal_store(__builtin_nontemporal_load(&g4[i]), &og4[i]);
}

extern "C" void kernel_launch(void* const* d_in, const int* in_sizes, int n_in,
                              void* d_out, int out_size, void* d_ws, size_t ws_size,
                              hipStream_t stream) {
    const float* v_in    = (const float*)d_in[0];
    const float* e_in    = (const float*)d_in[1];
    const float* u_in    = (const float*)d_in[2];
    const float* adj     = (const float*)d_in[3];
    const float* conEd   = (const float*)d_in[4];
    const float* edgeAdj = (const float*)d_in[5];
    float* out = (float*)d_out;

    char* scratch;
    long  eadjLimit4;
    bool  fallback;
    if (ws_size >= (size_t)NEED_WS) {
        scratch = (char*)d_ws;
        eadjLimit4 = EADJ_SZ / 4;
        fallback = false;
    } else {
        // place scratch in the tail of d_out (end of the edgeAdj segment);
        // mega's copy stays below it, tail_copy fills it afterwards.
        long out_bytes = (long)out_size * 4;
        scratch = (char*)d_out + (out_bytes - NEED_WS);
        eadjLimit4 = EADJ_SZ / 4 - NEED_WS / 16;
        fallback = true;
    }
    __bf16* adjT = (__bf16*)(scratch);
    __bf16* vT   = (__bf16*)(scratch + 33554432L);
    __bf16* eT   = (__bf16*)(scratch + 33554432L + 4194304L);

    prep_kernel<<<dim3(5632), dim3(256), 0, stream>>>(
        v_in, e_in, adj, adjT, vT, eT, out);
    mega_kernel<<<dim3(MM_BLOCKS + COPY_BLOCKS), dim3(512), 0, stream>>>(
        v_in, e_in, u_in, adj, conEd, edgeAdj, adjT, vT, eT, out, eadjLimit4);
    if (fallback) {
        tail_copy_kernel<<<dim3(512), dim3(256), 0, stream>>>(
            edgeAdj, out, eadjLimit4);
    }
}

// Round 6
// 863.303 us; speedup vs baseline: 1.0905x; 1.0905x over previous
//
#include <hip/hip_runtime.h>
#include <hip/hip_bf16.h>

// Problem constants
constexpr int BB = 4;     // batch
constexpr int NN = 2048;  // nodes
constexpr int EE = 4096;  // edges
constexpr int DD = 256;   // feature dim

// Sizes (floats)
constexpr long VOUT_SZ = (long)BB * NN * DD;          //  2,097,152
constexpr long E_SZ    = (long)BB * EE * DD;          //  4,194,304
constexpr long U_SZ    = (long)BB * DD;               //  1,024
constexpr long ADJ_SZ  = (long)BB * NN * NN;          // 16,777,216
constexpr long CON_SZ  = (long)BB * NN * EE;          // 33,554,432
constexpr long EADJ_SZ = (long)BB * EE * EE;          // 67,108,864

// Output segment float offsets (concat in return order)
constexpr long OUT_E    = VOUT_SZ;
constexpr long OUT_U    = OUT_E + E_SZ;
constexpr long OUT_ADJ  = OUT_U + U_SZ;
constexpr long OUT_CON  = OUT_ADJ + ADJ_SZ;
constexpr long OUT_EADJ = OUT_CON + CON_SZ;

constexpr int  MM_BLOCKS   = 256;   // 4 batch * 16 n-tiles * 4 k-chunks (full-D tiles)
constexpr int  COPY_BLOCKS = 768;
constexpr long NEED_WS     = 33554432L + 4194304L + 8388608L;  // adjT+vT+eT = 46,137,344 B

using bf16x4 = __attribute__((ext_vector_type(4))) __bf16;
using bf16x8 = __attribute__((ext_vector_type(8))) __bf16;
using f32x4  = __attribute__((ext_vector_type(4))) float;
using f32x4v = __attribute__((ext_vector_type(4))) float;  // NT-safe vector type

// ---------------------------------------------------------------------------
// prep: transpose + f32->bf16 convert (adj->adjT [n][m], v->vT [d][m],
// e->eT [d][e]) so GEMM staging reads are k-contiguous. FUSED extras:
//  - adj & e_in verbatim f32 pass-through copies into d_out
//  - vout pre-fill: out[vout] = v_in + u  (GEMM blocks then atomicAdd partials)
//  - u pass-through (on block 4096)
// ---------------------------------------------------------------------------
__global__ __launch_bounds__(256) void prep_kernel(
    const float* __restrict__ v_in, const float* __restrict__ e_in,
    const float* __restrict__ u_in, const float* __restrict__ adj,
    __bf16* __restrict__ adjT, __bf16* __restrict__ vT, __bf16* __restrict__ eT,
    float* __restrict__ out)
{
    __shared__ float tile[64][65];  // +1 pad: conflict-free transposed reads

    int bid = blockIdx.x;
    const float* in; __bf16* outT; float* pass; int R, C, t; bool isV = false;
    if (bid < 4096)      { in = adj;  outT = adjT; R = NN; C = NN; t = bid;
                           pass = out + OUT_ADJ; }
    else if (bid < 4608) { in = v_in; outT = vT;   R = NN; C = DD; t = bid - 4096;
                           pass = nullptr; isV = true; }
    else                 { in = e_in; outT = eT;   R = EE; C = DD; t = bid - 4608;
                           pass = out + OUT_E; }

    int perBatch = (R >> 6) * (C >> 6);
    int b  = t / perBatch;
    int tt = t % perBatch;
    int tilesC = C >> 6;
    int tr = tt / tilesC, tc = tt % tilesC;

    const size_t base = (size_t)b * R * C + (size_t)(tr * 64) * C + tc * 64;
    const float* inb  = in + base;
    float*       pb   = pass ? pass + base : nullptr;
    __bf16*     outb  = outT + (size_t)b * R * C + (size_t)(tc * 64) * R + tr * 64;

    int tid = threadIdx.x;

    if (bid == 4096) {  // u pass-through: 1024 floats = 256 f32x4
        f32x4v uv = reinterpret_cast<const f32x4v*>(u_in)[tid];
        reinterpret_cast<f32x4v*>(out + OUT_U)[tid] = uv;
    }

    #pragma unroll
    for (int it = 0; it < 4; ++it) {
        int q = tid + it * 256;           // 0..1023
        int r = q >> 4, c4 = (q & 15) << 2;
        f32x4v fv = *reinterpret_cast<const f32x4v*>(&inb[(size_t)r * C + c4]);
        tile[r][c4 + 0] = fv.x; tile[r][c4 + 1] = fv.y;
        tile[r][c4 + 2] = fv.z; tile[r][c4 + 3] = fv.w;
        if (pb) {
            __builtin_nontemporal_store(fv,
                reinterpret_cast<f32x4v*>(&pb[(size_t)r * C + c4]));
        } else if (isV) {
            // vout pre-fill = v + u
            f32x4v uv = *reinterpret_cast<const f32x4v*>(
                &u_in[(size_t)b * DD + tc * 64 + c4]);
            f32x4v s = fv + uv;
            *reinterpret_cast<f32x4v*>(
                &out[((size_t)b * NN + tr * 64 + r) * DD + tc * 64 + c4]) = s;
        }
    }
    __syncthreads();
    #pragma unroll
    for (int it = 0; it < 4; ++it) {
        int q = tid + it * 256;
        int c = q >> 4, r4 = (q & 15) << 2;
        bf16x4 h = { (__bf16)tile[r4 + 0][c], (__bf16)tile[r4 + 1][c],
                     (__bf16)tile[r4 + 2][c], (__bf16)tile[r4 + 3][c] };
        *reinterpret_cast<bf16x4*>(&outb[(size_t)c * R + r4]) = h;
    }
}

// ---------------------------------------------------------------------------
// mega: role-split blocks (512 threads each).
//   [0, 256): K-split GEMM. Block = (batch, n-tile of 128, k-chunk of 4).
//       Chunk c covers phase0 k in [c*512, c*512+512) (adjT @ v) and
//       phase1 k in [c*1024, c*1024+1024) (conEd @ e). Full D=256 tile,
//       8 waves (2x4), wave tile 64x64, mfma_f32_16x16x32_bf16.
//       Partials accumulate via unsafeAtomicAdd onto out (pre-filled v+u).
//   [256, 1024): float4 grid-stride NT copy of conEd/edgeAdj pass-throughs.
// LDS: per-row XOR granule swizzle -> conflict-free b128 reads (measured 0).
// ---------------------------------------------------------------------------
__global__ __launch_bounds__(512) void mega_kernel(
    const float* __restrict__ v_in, const float* __restrict__ e_in,
    const float* __restrict__ u_in, const float* __restrict__ adj,
    const float* __restrict__ conEd, const float* __restrict__ edgeAdj,
    const __bf16* __restrict__ adjT, const __bf16* __restrict__ vT,
    const __bf16* __restrict__ eT, float* __restrict__ out, long eadjLimit4)
{
    __shared__ __bf16 As[128 * 64];  // [row n][k], 16 KB, swizzled
    __shared__ __bf16 Bs[256 * 64];  // [col d][k], 32 KB, swizzled

    const int bid = blockIdx.x;
    const int tid = threadIdx.x;

    if (bid < MM_BLOCKS) {
        const int b  = bid >> 6;              // 64 jobs per batch
        const int r  = bid & 63;
        const int n0 = (r >> 2) << 7;         // n-tile of 128
        const int kc = r & 3;                 // k-chunk 0..3

        const __bf16* adjT_b = adjT + (size_t)b * NN * NN;
        const __bf16* vT_b   = vT   + (size_t)b * DD * NN;
        const __bf16* eT_b   = eT   + (size_t)b * DD * EE;
        const float*  con_b  = conEd + (size_t)b * NN * EE;

        const int lane = tid & 63, wid = tid >> 6;
        const int wr = wid >> 2, wc = wid & 3;   // waves 2x4 -> 64x64 each
        const int lr = lane & 15;
        const int lkq = lane >> 4;               // k quadrant 0..3

        f32x4 acc[4][4] = {};

        // 24 k-steps: s<8 -> phase0 (adjT@v, 512 wide), s>=8 -> phase1 (1024)
        for (int s = 0; s < 24; ++s) {
            const int phase = (s >= 8);
            const int k0 = phase ? kc * 1024 + (s - 8) * 64 : kc * 512 + s * 64;
            const int K  = phase ? EE : NN;
            const __bf16* bT = phase ? eT_b : vT_b;

            __syncthreads();
            if (!phase) {
                // As[n][k] <- adjT_b[n0+n][k0..k0+63]  (bf16, k-contiguous)
                #pragma unroll
                for (int it = 0; it < 2; ++it) {
                    int q = tid + it * 512;      // 0..1023
                    int n = q >> 3, g = q & 7;
                    bf16x8 vv = *reinterpret_cast<const bf16x8*>(
                        &adjT_b[(size_t)(n0 + n) * NN + k0 + (g << 3)]);
                    *reinterpret_cast<bf16x8*>(&As[(n << 6) + ((g ^ (n & 7)) << 3)]) = vv;
                }
            } else {
                // As[n][k] <- convert(con_b[n0+n][k0..k0+63])  (f32 src)
                #pragma unroll
                for (int it = 0; it < 4; ++it) {
                    int q = tid + it * 512;      // 0..2047
                    int n = q >> 4, e4 = (q & 15) << 2;
                    f32x4v fv = *reinterpret_cast<const f32x4v*>(
                        &con_b[(size_t)(n0 + n) * EE + k0 + e4]);
                    bf16x4 h = { (__bf16)fv.x, (__bf16)fv.y, (__bf16)fv.z, (__bf16)fv.w };
                    *reinterpret_cast<bf16x4*>(
                        &As[(n << 6) + (((e4 >> 3) ^ (n & 7)) << 3) + (e4 & 7)]) = h;
                }
            }
            // Bs[d][k] <- bT[d][k0..k0+63], all 256 d-rows
            #pragma unroll
            for (int it = 0; it < 4; ++it) {
                int q = tid + it * 512;          // 0..2047
                int dd = q >> 3, g = q & 7;
                bf16x8 vv = *reinterpret_cast<const bf16x8*>(
                    &bT[(size_t)dd * K + k0 + (g << 3)]);
                *reinterpret_cast<bf16x8*>(&Bs[(dd << 6) + ((g ^ (dd & 7)) << 3)]) = vv;
            }
            __syncthreads();

            #pragma unroll
            for (int ks = 0; ks < 2; ++ks) {
                const int gk = (ks << 2) + lkq;  // k granule 0..7
                bf16x8 a[4], bv[4];
                #pragma unroll
                for (int i = 0; i < 4; ++i) {
                    int row = (wr << 6) + (i << 4) + lr;
                    a[i] = *reinterpret_cast<const bf16x8*>(
                        &As[(row << 6) + ((gk ^ (row & 7)) << 3)]);
                }
                #pragma unroll
                for (int j = 0; j < 4; ++j) {
                    int col = (wc << 6) + (j << 4) + lr;
                    bv[j] = *reinterpret_cast<const bf16x8*>(
                        &Bs[(col << 6) + ((gk ^ (col & 7)) << 3)]);
                }
                #pragma unroll
                for (int i = 0; i < 4; ++i)
                    #pragma unroll
                    for (int j = 0; j < 4; ++j)
                        acc[i][j] = __builtin_amdgcn_mfma_f32_16x16x32_bf16(
                            a[i], bv[j], acc[i][j], 0, 0, 0);
            }
        }

        // epilogue: atomic accumulate partial sums onto out (= v + u + partials)
        #pragma unroll
        for (int i = 0; i < 4; ++i) {
            #pragma unroll
            for (int r4 = 0; r4 < 4; ++r4) {
                int n = n0 + (wr << 6) + (i << 4) + (lkq << 2) + r4;
                #pragma unroll
                for (int j = 0; j < 4; ++j) {
                    int col = (wc << 6) + (j << 4) + lr;
                    unsafeAtomicAdd(&out[((size_t)b * NN + n) * DD + col],
                                    acc[i][j][r4]);
                }
            }
        }
    } else {
        // ------- copy role: conEd, edgeAdj (adj/e/u/vout handled by prep) ---
        const long i0 = (long)(bid - MM_BLOCKS) * 512 + tid;
        const long stride = (long)COPY_BLOCKS * 512;

        const f32x4v* c4 = reinterpret_cast<const f32x4v*>(conEd);
        f32x4v*      oc4 = reinterpret_cast<f32x4v*>(out + OUT_CON);
        for (long i = i0; i < CON_SZ / 4; i += stride)
            __builtin_nontemporal_store(__builtin_nontemporal_load(&c4[i]), &oc4[i]);

        const f32x4v* g4 = reinterpret_cast<const f32x4v*>(edgeAdj);
        f32x4v*      og4 = reinterpret_cast<f32x4v*>(out + OUT_EADJ);
        for (long i = i0; i < eadjLimit4; i += stride)
            __builtin_nontemporal_store(__builtin_nontemporal_load(&g4[i]), &og4[i]);
    }
}

// tail copy for the fallback path (scratch lived in d_out tail): finishes the
// edgeAdj segment [start4, EADJ_SZ/4)
__global__ __launch_bounds__(256) void tail_copy_kernel(
    const float* __restrict__ edgeAdj, float* __restrict__ out, long start4)
{
    const long i0 = start4 + (long)blockIdx.x * 256 + threadIdx.x;
    const long stride = (long)gridDim.x * 256;
    const f32x4v* g4 = reinterpret_cast<const f32x4v*>(edgeAdj);
    f32x4v*      og4 = reinterpret_cast<f32x4v*>(out + OUT_EADJ);
    for (long i = i0; i < EADJ_SZ / 4; i += stride)
        __builtin_nontemporal_store(__builtin_nontemporal_load(&g4[i]), &og4[i]);
}

extern "C" void kernel_launch(void* const* d_in, const int* in_sizes, int n_in,
                              void* d_out, int out_size, void* d_ws, size_t ws_size,
                              hipStream_t stream) {
    const float* v_in    = (const float*)d_in[0];
    const float* e_in    = (const float*)d_in[1];
    const float* u_in    = (const float*)d_in[2];
    const float* adj     = (const float*)d_in[3];
    const float* conEd   = (const float*)d_in[4];
    const float* edgeAdj = (const float*)d_in[5];
    float* out = (float*)d_out;

    char* scratch;
    long  eadjLimit4;
    bool  fallback;
    if (ws_size >= (size_t)NEED_WS) {
        scratch = (char*)d_ws;
        eadjLimit4 = EADJ_SZ / 4;
        fallback = false;
    } else {
        // place scratch in the tail of d_out (end of the edgeAdj segment);
        // mega's copy stays below it, tail_copy fills it afterwards.
        long out_bytes = (long)out_size * 4;
        scratch = (char*)d_out + (out_bytes - NEED_WS);
        eadjLimit4 = EADJ_SZ / 4 - (NEED_WS + 15) / 16;  // ceil: never overlap scratch
        fallback = true;
    }
    __bf16* adjT = (__bf16*)(scratch);
    __bf16* vT   = (__bf16*)(scratch + 33554432L);
    __bf16* eT   = (__bf16*)(scratch + 33554432L + 4194304L);

    prep_kernel<<<dim3(5632), dim3(256), 0, stream>>>(
        v_in, e_in, u_in, adj, adjT, vT, eT, out);
    mega_kernel<<<dim3(MM_BLOCKS + COPY_BLOCKS), dim3(512), 0, stream>>>(
        v_in, e_in, u_in, adj, conEd, edgeAdj, adjT, vT, eT, out, eadjLimit4);
    if (fallback) {
        tail_copy_kernel<<<dim3(512), dim3(256), 0, stream>>>(
            edgeAdj, out, eadjLimit4);
    }
}